// Round 4
// baseline (83.569 us; speedup 1.0000x reference)
//
#include <hip/hip_runtime.h>

#define EPS 1e-7f

constexpr int NPRED  = 8192;
constexpr int NTGT   = 4096;
constexpr int BLOCK  = 256;          // 4 waves
constexpr int PW     = 4;            // preds per wave
constexpr int PPB    = 16;           // preds per block (4 waves * 4)
constexpr int TSPLIT = 8;            // target slices
constexpr int TCHUNK = NTGT / TSPLIT;    // 512 targets per block (8 KB LDS)
constexpr int GRID_P = NPRED / PPB;      // 512
constexpr int GRID   = GRID_P * TSPLIT;  // 4096 blocks -> 8+ blocks/CU resident

__device__ __forceinline__ unsigned sortable_key(float f) {
  unsigned b = __float_as_uint(f);
  return (b & 0x80000000u) ? ~b : (b | 0x80000000u);
}

__global__ __launch_bounds__(BLOCK, 8)   // pin VGPR <= 64 -> 8 waves/SIMD
void diou_argmax(const float4* __restrict__ pred,
                 const float4* __restrict__ tgt,
                 unsigned long long* __restrict__ pk) {
  __shared__ float4 sT[TCHUNK];
  const int lane  = threadIdx.x & 63;
  const int wave  = threadIdx.x >> 6;
  const int pblk  = blockIdx.x % GRID_P;
  const int tq    = blockIdx.x / GRID_P;
  const int tbase = tq * TCHUNK;
  const int pbase = pblk * PPB + wave * PW;

  // stage this block's target slice (8 KB)
  for (int t = threadIdx.x; t < TCHUNK; t += BLOCK) sT[t] = tgt[tbase + t];

  float4 p[PW];
  float  paeps[PW];
  float  bestV[PW];
  int    bestI[PW];
#pragma unroll
  for (int i = 0; i < PW; ++i) {
    p[i]     = pred[pbase + i];
    paeps[i] = (p[i].z - p[i].x) * (p[i].w - p[i].y) + EPS;  // xyxy-interp area + eps
    bestV[i] = -INFINITY;
    bestI[i] = 0;
  }
  __syncthreads();

#pragma unroll 4
  for (int t0 = 0; t0 < TCHUNK; t0 += 64) {
    const int t = t0 + lane;          // chunk-local index, 0..511
    float4 tb = sT[t];
    float  ta = (tb.z - tb.x) * (tb.w - tb.y);
#pragma unroll
    for (int i = 0; i < PW; ++i) {
      float w = fminf(p[i].z, tb.z) - fmaxf(p[i].x, tb.x);
      float h = fminf(p[i].w, tb.w) - fmaxf(p[i].y, tb.y);
      w = fmaxf(w, 0.f);
      h = fmaxf(h, 0.f);
      float inter = w * h;
      float denom = (paeps[i] + ta) - inter;
      float iou   = inter * __builtin_amdgcn_rcpf(denom);
      iou += 0.0f;                    // normalize -0 -> +0 (cross-block tie semantics)
      // strict > keeps the FIRST max within a lane (indices ascend)
      if (iou > bestV[i]) { bestV[i] = iou; bestI[i] = t; }
    }
  }

  // cross-lane argmax: larger value wins; tie -> smaller index
#pragma unroll
  for (int i = 0; i < PW; ++i) {
    float v  = bestV[i];
    int   ix = bestI[i];
    for (int off = 32; off > 0; off >>= 1) {
      float ov = __shfl_down(v, off, 64);
      int   oi = __shfl_down(ix, off, 64);
      if (ov > v || (ov == v && oi < ix)) { v = ov; ix = oi; }
    }
    if (lane == 0) {
      unsigned long long packed =
          ((unsigned long long)sortable_key(v) << 32) |
          (unsigned)(NTGT - 1 - (tbase + ix));          // tie -> smaller global index
      atomicMax(&pk[pbase + i], packed);
    }
  }
}

// fused gather + DIoU + full reduction + finalize: one 1024-thread block
__global__ __launch_bounds__(1024)
void diou_gather_finalize(const float4* __restrict__ pred,
                          const float4* __restrict__ tgt,
                          const unsigned long long* __restrict__ pk,
                          float* __restrict__ out) {
  __shared__ float sP[16];
  const int tid  = threadIdx.x;
  const int lane = tid & 63;

  float v = 0.f;
  for (int j = tid; j < NPRED; j += 1024) {
    float4 p  = pred[j];
    int    ix = NTGT - 1 - (int)(unsigned)(pk[j] & 0xFFFFFFFFu);
    float4 t  = tgt[ix];

    // reference reinterprets columns as (cx, cy, w, h)
    float phw = 0.5f * p.z, phh = 0.5f * p.w;
    float thw = 0.5f * t.z, thh = 0.5f * t.w;
    float pltx = p.x - phw, plty = p.y - phh;
    float prbx = p.x + phw, prby = p.y + phh;
    float tltx = t.x - thw, tlty = t.y - thh;
    float trbx = t.x + thw, trby = t.y + thh;

    float iw = fmaxf(fminf(prbx, trbx) - fmaxf(pltx, tltx), 0.f);
    float ih = fmaxf(fminf(prby, trby) - fmaxf(plty, tlty), 0.f);
    float inter = iw * ih;
    float parea = p.z * p.w;
    float tarea = t.z * t.w;
    float iou   = inter / (parea + tarea - inter + EPS);

    float dx = p.x - t.x, dy = p.y - t.y;
    float cd = dx * dx + dy * dy;

    float ew = fmaxf(prbx, trbx) - fminf(pltx, tltx);
    float eh = fmaxf(prby, trby) - fminf(plty, tlty);
    float diag = ew * ew + eh * eh;

    v += iou - cd / (diag + EPS);
  }

  for (int off = 32; off > 0; off >>= 1) v += __shfl_down(v, off, 64);
  if (lane == 0) sP[tid >> 6] = v;
  __syncthreads();
  if (tid == 0) {
    float s = 0.f;
#pragma unroll
    for (int i = 0; i < 16; ++i) s += sP[i];
    out[0] = 1.f - s * (1.f / (float)NPRED);
  }
}

extern "C" void kernel_launch(void* const* d_in, const int* in_sizes, int n_in,
                              void* d_out, int out_size, void* d_ws, size_t ws_size,
                              hipStream_t stream) {
  const float4* pred = (const float4*)d_in[0];
  const float4* tgt  = (const float4*)d_in[1];
  unsigned long long* pk = (unsigned long long*)d_ws;   // 8192 * 8 B

  // zero packed-argmax array (key 0 < any real iou key)
  hipMemsetAsync(pk, 0, NPRED * sizeof(unsigned long long), stream);
  diou_argmax<<<GRID, BLOCK, 0, stream>>>(pred, tgt, pk);
  diou_gather_finalize<<<1, 1024, 0, stream>>>(pred, tgt, pk, (float*)d_out);
}

// Round 5
// 80.369 us; speedup vs baseline: 1.0398x; 1.0398x over previous
//
#include <hip/hip_runtime.h>

#define EPS 1e-7f

constexpr int NPRED  = 8192;
constexpr int NTGT   = 4096;
constexpr int BLOCK  = 256;          // 4 waves
constexpr int PW     = 4;            // preds per wave
constexpr int PPB    = 16;           // preds per block (4 waves * 4)
constexpr int TSPLIT = 4;            // target slices
constexpr int TCHUNK = NTGT / TSPLIT;    // 1024 targets per block (16 KB LDS)
constexpr int GRID_P = NPRED / PPB;      // 512
constexpr int GRID   = GRID_P * TSPLIT;  // 2048 blocks -> exactly 8/CU resident
constexpr int GBLK   = 32;               // gather blocks

__device__ __forceinline__ unsigned sortable_key(float f) {
  unsigned b = __float_as_uint(f);
  return (b & 0x80000000u) ? ~b : (b | 0x80000000u);
}

__global__ __launch_bounds__(BLOCK, 8)   // pin VGPR <= 64 -> 8 waves/SIMD
void diou_argmax(const float4* __restrict__ pred,
                 const float4* __restrict__ tgt,
                 unsigned long long* __restrict__ pk) {
  __shared__ float4 sT[TCHUNK];
  const int lane  = threadIdx.x & 63;
  const int wave  = threadIdx.x >> 6;
  const int pblk  = blockIdx.x % GRID_P;
  const int tq    = blockIdx.x / GRID_P;
  const int tbase = tq * TCHUNK;
  const int pbase = pblk * PPB + wave * PW;

  // stage this block's target slice (16 KB)
#pragma unroll
  for (int t = threadIdx.x; t < TCHUNK; t += BLOCK) sT[t] = tgt[tbase + t];

  float4 p[PW];
  float  paeps[PW];
  float  bestV[PW];
  int    bestI[PW];
#pragma unroll
  for (int i = 0; i < PW; ++i) {
    p[i]     = pred[pbase + i];
    paeps[i] = (p[i].z - p[i].x) * (p[i].w - p[i].y) + EPS;  // xyxy-interp area + eps
    bestV[i] = -INFINITY;
    bestI[i] = 0;
  }
  __syncthreads();

#pragma unroll 4
  for (int t0 = 0; t0 < TCHUNK; t0 += 64) {
    const int t = t0 + lane;          // chunk-local index, 0..1023
    float4 tb = sT[t];
    float  ta = (tb.z - tb.x) * (tb.w - tb.y);
#pragma unroll
    for (int i = 0; i < PW; ++i) {
      float w = fminf(p[i].z, tb.z) - fmaxf(p[i].x, tb.x);
      float h = fminf(p[i].w, tb.w) - fmaxf(p[i].y, tb.y);
      w = fmaxf(w, 0.f);
      h = fmaxf(h, 0.f);
      float inter = w * h;
      float denom = (paeps[i] + ta) - inter;
      float iou   = inter * __builtin_amdgcn_rcpf(denom);
      // strict > keeps the FIRST max within a lane (indices ascend);
      // +-0 compare equal under > and ==, so no normalization needed here
      if (iou > bestV[i]) { bestV[i] = iou; bestI[i] = t; }
    }
  }

  // cross-lane argmax: larger value wins; tie -> smaller index
#pragma unroll
  for (int i = 0; i < PW; ++i) {
    float v  = bestV[i];
    int   ix = bestI[i];
    for (int off = 32; off > 0; off >>= 1) {
      float ov = __shfl_down(v, off, 64);
      int   oi = __shfl_down(ix, off, 64);
      if (ov > v || (ov == v && oi < ix)) { v = ov; ix = oi; }
    }
    if (lane == 0) {
      v += 0.0f;                       // normalize -0 -> +0 for key packing only
      unsigned long long packed =
          ((unsigned long long)sortable_key(v) << 32) |
          (unsigned)(NTGT - 1 - (tbase + ix));          // tie -> smaller global index
      atomicMax(&pk[pbase + i], packed);
    }
  }
}

// parallel gather + DIoU + reduce; last finished block finalizes
__global__ __launch_bounds__(BLOCK)
void diou_gather(const float4* __restrict__ pred,
                 const float4* __restrict__ tgt,
                 const unsigned long long* __restrict__ pk,
                 float* __restrict__ acc,
                 unsigned* __restrict__ cnt,
                 float* __restrict__ out) {
  __shared__ float sP[4];
  const int tid  = blockIdx.x * BLOCK + threadIdx.x;
  const int lane = threadIdx.x & 63;
  const int wave = threadIdx.x >> 6;

  float4 p  = pred[tid];
  int    ix = NTGT - 1 - (int)(unsigned)(pk[tid] & 0xFFFFFFFFu);
  float4 t  = tgt[ix];

  // reference reinterprets columns as (cx, cy, w, h)
  float phw = 0.5f * p.z, phh = 0.5f * p.w;
  float thw = 0.5f * t.z, thh = 0.5f * t.w;
  float pltx = p.x - phw, plty = p.y - phh;
  float prbx = p.x + phw, prby = p.y + phh;
  float tltx = t.x - thw, tlty = t.y - thh;
  float trbx = t.x + thw, trby = t.y + thh;

  float iw = fmaxf(fminf(prbx, trbx) - fmaxf(pltx, tltx), 0.f);
  float ih = fmaxf(fminf(prby, trby) - fmaxf(plty, tlty), 0.f);
  float inter = iw * ih;
  float parea = p.z * p.w;
  float tarea = t.z * t.w;
  float iou   = inter / (parea + tarea - inter + EPS);

  float dx = p.x - t.x, dy = p.y - t.y;
  float cd = dx * dx + dy * dy;

  float ew = fmaxf(prbx, trbx) - fminf(pltx, tltx);
  float eh = fmaxf(prby, trby) - fminf(plty, tlty);
  float diag = ew * ew + eh * eh;

  float v = iou - cd / (diag + EPS);

  for (int off = 32; off > 0; off >>= 1) v += __shfl_down(v, off, 64);
  if (lane == 0) sP[wave] = v;
  __syncthreads();
  if (threadIdx.x == 0) {
    atomicAdd(acc, sP[0] + sP[1] + sP[2] + sP[3]);
    __threadfence();                               // release acc before cnt
    if (atomicAdd(cnt, 1u) == GBLK - 1) {          // last block finalizes
      float s = atomicAdd(acc, 0.0f);              // coherent read of full sum
      out[0] = 1.f - s * (1.f / (float)NPRED);
    }
  }
}

extern "C" void kernel_launch(void* const* d_in, const int* in_sizes, int n_in,
                              void* d_out, int out_size, void* d_ws, size_t ws_size,
                              hipStream_t stream) {
  const float4* pred = (const float4*)d_in[0];
  const float4* tgt  = (const float4*)d_in[1];

  unsigned long long* pk = (unsigned long long*)d_ws;               // 64 KB
  float*    acc = (float*)   ((char*)d_ws + NPRED * 8);             // +4 B
  unsigned* cnt = (unsigned*)((char*)d_ws + NPRED * 8 + 4);         // +4 B

  // zero pk (key 0 < any real iou key) + acc + cnt in one memset
  hipMemsetAsync(d_ws, 0, NPRED * 8 + 8, stream);
  diou_argmax<<<GRID, BLOCK, 0, stream>>>(pred, tgt, pk);
  diou_gather<<<GBLK, BLOCK, 0, stream>>>(pred, tgt, pk, acc, cnt, (float*)d_out);
}

// Round 7
// 77.177 us; speedup vs baseline: 1.0828x; 1.0414x over previous
//
#include <hip/hip_runtime.h>

#define EPS 1e-7f

constexpr int NPRED = 8192;
constexpr int NTGT  = 4096;
constexpr int BLOCK = 512;             // 8 waves
constexpr int PPB   = 8;               // 1 pred per wave
constexpr int GRID  = NPRED / PPB;     // 1024 blocks -> 4/CU, 32 waves/CU (100% occ)
constexpr int CH    = 1024;            // targets per staged chunk (16 KB + 4 KB LDS)
constexpr int NCH   = NTGT / CH;       // 4 chunks

__global__ __launch_bounds__(BLOCK, 8)
void diou_main(const float4* __restrict__ pred,
               const float4* __restrict__ tgt,
               float* __restrict__ partial) {
  __shared__ float4 sT[CH];            // 16 KB: target boxes
  __shared__ float  sA[CH];            //  4 KB: target areas (no eps)
  __shared__ float  sP[PPB];
  const int lane = threadIdx.x & 63;
  const int wave = threadIdx.x >> 6;
  const int pidx = blockIdx.x * PPB + wave;

  const float4 p = pred[pidx];                              // wave-uniform -> SGPRs
  const float paeps = (p.z - p.x) * (p.w - p.y) + EPS;      // xyxy-interp area + eps

  float bestV = -INFINITY;
  int   bestB = 0;                     // wave-uniform candidate base (chunk*CH + t0)

  for (int c = 0; c < NCH; ++c) {
    __syncthreads();                   // protect sT/sA reuse across chunks
    for (int t = threadIdx.x; t < CH; t += BLOCK) {
      float4 tb = tgt[c * CH + t];
      sT[t] = tb;
      sA[t] = (tb.z - tb.x) * (tb.w - tb.y);
    }
    __syncthreads();
    const int cb = c * CH;
#pragma unroll 4
    for (int t0 = 0; t0 < CH; t0 += 64) {
      float4 tb = sT[t0 + lane];       // vaddr = lane*16, t0*16 in offset imm
      float  ta = sA[t0 + lane];
      float w = fminf(p.z, tb.z) - fmaxf(p.x, tb.x);
      float h = fminf(p.w, tb.w) - fmaxf(p.y, tb.y);
      w = fmaxf(w, 0.f);
      h = fmaxf(h, 0.f);
      float inter = w * h;
      float den   = (paeps + ta) - inter;
      float iou   = inter * __builtin_amdgcn_rcpf(den);
      // strict > keeps FIRST max (lane's candidates ascend in t0);
      // bestB is uniform -> cndmask with scalar source, index add hoisted out
      if (iou > bestV) { bestV = iou; bestB = cb + t0; }
    }
  }

  // per-lane global index, then cross-lane argmax (tie -> smaller index)
  int   ix = bestB + lane;
  float v  = bestV;
  for (int off = 32; off > 0; off >>= 1) {
    float ov = __shfl_down(v, off, 64);
    int   oi = __shfl_down(ix, off, 64);
    if (ov > v || (ov == v && oi < ix)) { v = ov; ix = oi; }
  }

  if (lane == 0) {
    float4 t = tgt[ix];
    // reference reinterprets columns as (cx, cy, w, h)
    float phw = 0.5f * p.z, phh = 0.5f * p.w;
    float thw = 0.5f * t.z, thh = 0.5f * t.w;
    float pltx = p.x - phw, plty = p.y - phh;
    float prbx = p.x + phw, prby = p.y + phh;
    float tltx = t.x - thw, tlty = t.y - thh;
    float trbx = t.x + thw, trby = t.y + thh;

    float iw = fmaxf(fminf(prbx, trbx) - fmaxf(pltx, tltx), 0.f);
    float ih = fmaxf(fminf(prby, trby) - fmaxf(plty, tlty), 0.f);
    float inter = iw * ih;
    float parea = p.z * p.w;
    float tarea = t.z * t.w;
    float iou   = inter / (parea + tarea - inter + EPS);

    float dx = p.x - t.x, dy = p.y - t.y;
    float cd = dx * dx + dy * dy;

    float ew = fmaxf(prbx, trbx) - fminf(pltx, tltx);
    float eh = fmaxf(prby, trby) - fminf(plty, tlty);
    float diag = ew * ew + eh * eh;

    sP[wave] = iou - cd / (diag + EPS);
  }
  __syncthreads();
  if (threadIdx.x == 0) {
    float s = 0.f;
#pragma unroll
    for (int i = 0; i < PPB; ++i) s += sP[i];
    partial[blockIdx.x] = s;             // plain store: no init, no atomics
  }
}

__global__ __launch_bounds__(1024)
void diou_finalize(const float* __restrict__ partial,
                   float* __restrict__ out) {
  __shared__ float sW[16];
  const int tid  = threadIdx.x;
  const int lane = tid & 63;
  float v = partial[tid];                // GRID == 1024 partials, one per thread
  for (int off = 32; off > 0; off >>= 1) v += __shfl_down(v, off, 64);
  if (lane == 0) sW[tid >> 6] = v;
  __syncthreads();
  if (tid == 0) {
    float s = 0.f;
#pragma unroll
    for (int i = 0; i < 16; ++i) s += sW[i];
    out[0] = 1.f - s * (1.f / (float)NPRED);
  }
}

extern "C" void kernel_launch(void* const* d_in, const int* in_sizes, int n_in,
                              void* d_out, int out_size, void* d_ws, size_t ws_size,
                              hipStream_t stream) {
  const float4* pred = (const float4*)d_in[0];
  const float4* tgt  = (const float4*)d_in[1];
  float* partial = (float*)d_ws;         // 1024 * 4 B, fully written each call

  diou_main<<<GRID, BLOCK, 0, stream>>>(pred, tgt, partial);
  diou_finalize<<<1, 1024, 0, stream>>>(partial, (float*)d_out);
}